// Round 1
// baseline (453.190 us; speedup 1.0000x reference)
//
#include <hip/hip_runtime.h>
#include <hip/hip_bf16.h>
#include <stdint.h>

// Problem constants
#define BB 4
#define TT 24
#define NN 325          // sequence length per (b,t)
#define DD 512
#define NH 8
#define DKH 64          // d_k per head
#define MROWS (BB*TT*NN)   // 31200 total rows
#define BTC (BB*TT)        // 96

typedef __attribute__((ext_vector_type(4))) float f32x4;
typedef __attribute__((ext_vector_type(8))) short s16x8;
typedef __attribute__((ext_vector_type(4))) unsigned int u32x4;

__device__ __forceinline__ unsigned short f2bf(float f) {
    union { float f; unsigned int u; } x; x.f = f;
    unsigned int u = x.u;
    u += 0x7fffu + ((u >> 16) & 1u);   // RNE
    return (unsigned short)(u >> 16);
}
__device__ __forceinline__ unsigned int pack2(float a, float b) {
    return (unsigned int)f2bf(a) | ((unsigned int)f2bf(b) << 16);
}

// ---------------------------------------------------------------------------
// K0: weight prep. Permute head-interleaved columns (d = dk*8+h  ->  h*64+dk),
// transpose to [n][k] layout, convert to bf16.
//   WtH[i][c'][e] = Wh[i][e][colmap(c')]      (3x512x512 bf16)
//   WtO[c][e']    = Wo[rowmap(e')][c]          (512x512 bf16)
//   biasp[i][c']  = bias[i][colmap(c')]        (fp32)
// colmap(x) = rowmap(x) = ((x&63)<<3) | (x>>6)
// ---------------------------------------------------------------------------
__global__ void prep_kernel(const float* __restrict__ Wh, const float* __restrict__ bias,
                            const float* __restrict__ Wo,
                            unsigned short* __restrict__ WtH, unsigned short* __restrict__ WtO,
                            float* __restrict__ biasp)
{
    int idx = blockIdx.x * 256 + threadIdx.x;
    if (idx < 3*512*512) {
        int i = idx >> 18; int rem = idx & 262143;
        int cp = rem >> 9; int e = rem & 511;
        int c = ((cp & 63) << 3) | (cp >> 6);
        WtH[idx] = f2bf(Wh[(i << 18) + (e << 9) + c]);
        return;
    }
    int idx2 = idx - 3*512*512;
    if (idx2 >= 0 && idx2 < 512*512) {
        int c = idx2 >> 9; int ep = idx2 & 511;
        int row = ((ep & 63) << 3) | (ep >> 6);
        WtO[idx2] = f2bf(Wo[(row << 9) + c]);
        return;
    }
    int idx3 = idx2 - 512*512;
    if (idx3 >= 0 && idx3 < 3*512) {
        int i = idx3 >> 9; int cp = idx3 & 511;
        int c = ((cp & 63) << 3) | (cp >> 6);
        biasp[idx3] = bias[(i << 9) + c];
    }
}

// ---------------------------------------------------------------------------
// K1: QKV projection GEMM.  Y[z] = A[z] (fp32, MxK) @ W[z] (bf16 [n][k]) + bias
// Tiles: BM=128 BN=128 BK=64, 256 threads (4 waves, 2x2), each wave 64x64.
// LDS XOR-swizzle: 16B granule index = row*8 + (slot ^ (row&7)).
// ---------------------------------------------------------------------------
__global__ __launch_bounds__(256) void proj_gemm(
    const float* __restrict__ Aq, const float* __restrict__ Ak, const float* __restrict__ Av,
    const unsigned short* __restrict__ Wt, const float* __restrict__ biasp,
    unsigned short* __restrict__ Yq, unsigned short* __restrict__ Yk, unsigned short* __restrict__ Yv)
{
    __shared__ unsigned short As[128*64];
    __shared__ unsigned short Bs[128*64];

    int z = blockIdx.z;
    const float* A = (z == 0) ? Aq : ((z == 1) ? Ak : Av);
    unsigned short* Y = (z == 0) ? Yq : ((z == 1) ? Yk : Yv);
    const unsigned short* Bt = Wt + z * 512 * 512;
    const float* bias = biasp + z * 512;

    int mtile = blockIdx.x, ntile = blockIdx.y;
    int t = threadIdx.x;
    int srow = t >> 1, shalf = t & 1;          // staging: 2 threads/row
    int wid = t >> 6, lane = t & 63;
    int wm = wid >> 1, wn = wid & 1;
    int lm = lane & 15, lg = lane >> 4;

    f32x4 acc[4][4] = {};

    long arow = (long)mtile * 128 + srow;
    bool avalid = arow < MROWS;
    const float* aptr = A + arow * 512 + shalf * 32;
    const unsigned short* bptr = Bt + (ntile * 128 + srow) * 512 + shalf * 32;

    float4 afl[8];
    u32x4 bbuf[4];
    // prologue loads (k0 = 0)
    if (avalid) {
        const float4* ap = (const float4*)aptr;
        #pragma unroll
        for (int i = 0; i < 8; ++i) afl[i] = ap[i];
    } else {
        #pragma unroll
        for (int i = 0; i < 8; ++i) { afl[i].x = afl[i].y = afl[i].z = afl[i].w = 0.f; }
    }
    {
        const u32x4* bp = (const u32x4*)bptr;
        #pragma unroll
        for (int i = 0; i < 4; ++i) bbuf[i] = bp[i];
    }

    for (int kk = 0; kk < 8; ++kk) {
        __syncthreads();          // previous compute done reading LDS
        {
            u32x4* asl = (u32x4*)As;
            u32x4* bsl = (u32x4*)Bs;
            int base = srow * 8, sw = srow & 7;
            #pragma unroll
            for (int s = 0; s < 4; ++s) {
                int slot = shalf * 4 + s;
                u32x4 aw;
                float4 x0 = afl[2*s], x1 = afl[2*s+1];
                aw[0] = pack2(x0.x, x0.y); aw[1] = pack2(x0.z, x0.w);
                aw[2] = pack2(x1.x, x1.y); aw[3] = pack2(x1.z, x1.w);
                asl[base + (slot ^ sw)] = aw;
                bsl[base + (slot ^ sw)] = bbuf[s];
            }
        }
        __syncthreads();
        if (kk < 7) {             // prefetch next K-slab into regs (overlaps MFMA)
            int k0 = (kk + 1) * 64;
            if (avalid) {
                const float4* ap = (const float4*)(aptr + k0);
                #pragma unroll
                for (int i = 0; i < 8; ++i) afl[i] = ap[i];
            }
            const u32x4* bp = (const u32x4*)(bptr + k0);
            #pragma unroll
            for (int i = 0; i < 4; ++i) bbuf[i] = bp[i];
        }
        #pragma unroll
        for (int ks = 0; ks < 2; ++ks) {
            s16x8 af[4], bfr[4];
            #pragma unroll
            for (int mf = 0; mf < 4; ++mf) {
                int row = wm * 64 + mf * 16 + lm;
                af[mf] = ((const s16x8*)As)[row * 8 + ((ks*4 + lg) ^ (row & 7))];
            }
            #pragma unroll
            for (int nf = 0; nf < 4; ++nf) {
                int row = wn * 64 + nf * 16 + lm;
                bfr[nf] = ((const s16x8*)Bs)[row * 8 + ((ks*4 + lg) ^ (row & 7))];
            }
            #pragma unroll
            for (int mf = 0; mf < 4; ++mf)
                #pragma unroll
                for (int nf = 0; nf < 4; ++nf)
                    acc[mf][nf] = __builtin_amdgcn_mfma_f32_16x16x32_bf16(af[mf], bfr[nf], acc[mf][nf], 0, 0, 0);
        }
    }

    // epilogue: + bias, cast bf16, store (C layout: col=lane&15, row=(lane>>4)*4+j)
    #pragma unroll
    for (int nf = 0; nf < 4; ++nf) {
        int gcol = ntile * 128 + wn * 64 + nf * 16 + lm;
        float bv = bias[gcol];
        #pragma unroll
        for (int mf = 0; mf < 4; ++mf) {
            #pragma unroll
            for (int j = 0; j < 4; ++j) {
                long grow = (long)mtile * 128 + wm * 64 + mf * 16 + lg * 4 + j;
                if (grow < MROWS)
                    Y[grow * 512 + gcol] = f2bf(acc[mf][nf][j] + bv);
            }
        }
    }
}

// ---------------------------------------------------------------------------
// K2: attention. Block = (Q-chunk of 64 rows, head h, bt). 4 waves x 16 Q rows.
// Per 64-KV tile: stage K rows + V^T (both swizzled), S = Q K^T (MFMA),
// online softmax (width-16 shuffle reduce), P->LDS (bf16), O += P V (MFMA).
// ---------------------------------------------------------------------------
__global__ __launch_bounds__(256) void attn_kernel(
    const unsigned short* __restrict__ Qw, const unsigned short* __restrict__ Kw,
    const unsigned short* __restrict__ Vw, unsigned short* __restrict__ Ow)
{
    __shared__ unsigned short Qs[64*64];
    __shared__ unsigned short Ks[64*64];
    __shared__ unsigned short Vts[64*64];
    __shared__ unsigned short Ps[64*64];

    int qc = blockIdx.x;      // 0..5
    int h  = blockIdx.y;      // 0..7
    int bt = blockIdx.z;      // 0..95
    int t = threadIdx.x;
    int wid = t >> 6, lane = t & 63, lm = lane & 15, lg = lane >> 4;

    long rowbase = (long)bt * NN;
    int colbase = h * 64;
    int q0 = qc * 64;

    // stage Q chunk (zero-fill invalid rows)
    {
        int i = t >> 2, quarter = t & 3;
        const u32x4* src = (const u32x4*)(Qw + (rowbase + q0 + i) * 512 + colbase);
        u32x4* dst = (u32x4*)Qs;
        #pragma unroll
        for (int s = 0; s < 2; ++s) {
            int slot = quarter + s * 4;
            u32x4 v = 0;
            if (q0 + i < NN) v = src[slot];
            dst[i * 8 + (slot ^ (i & 7))] = v;
        }
    }
    __syncthreads();
    s16x8 aq[2];
    {
        int row = wid * 16 + lm;
        aq[0] = ((const s16x8*)Qs)[row * 8 + ((0 + lg) ^ (row & 7))];
        aq[1] = ((const s16x8*)Qs)[row * 8 + ((4 + lg) ^ (row & 7))];
    }

    f32x4 oacc[4] = {};
    float mrow[4], lrow[4];
    #pragma unroll
    for (int j = 0; j < 4; ++j) { mrow[j] = -__builtin_inff(); lrow[j] = 0.f; }

    for (int kv0 = 0; kv0 < NN; kv0 += 64) {
        __syncthreads();   // previous tile's LDS reads complete
        // stage K tile
        {
            int i = t >> 2, quarter = t & 3;
            const u32x4* src = (const u32x4*)(Kw + (rowbase + kv0 + i) * 512 + colbase);
            u32x4* dst = (u32x4*)Ks;
            #pragma unroll
            for (int s = 0; s < 2; ++s) {
                int slot = quarter + s * 4;
                u32x4 v = 0;
                if (kv0 + i < NN) v = src[slot];
                dst[i * 8 + (slot ^ (i & 7))] = v;
            }
        }
        // stage V^T tile (Vts[dk][kv])
        {
            int i = t >> 2, quarter = t & 3;
            unsigned short vb[16] __attribute__((aligned(16)));
            if (kv0 + i < NN) {
                const u32x4* src = (const u32x4*)(Vw + (rowbase + kv0 + i) * 512 + colbase + quarter * 16);
                *((u32x4*)vb) = src[0];
                *((u32x4*)(vb + 8)) = src[1];
            } else {
                #pragma unroll
                for (int x = 0; x < 16; ++x) vb[x] = 0;
            }
            #pragma unroll
            for (int x = 0; x < 16; ++x) {
                int dk = quarter * 16 + x;
                Vts[dk * 64 + (i ^ ((dk & 7) << 3))] = vb[x];
            }
        }
        __syncthreads();

        // S = Q K^T for this wave's 16 rows x 64 kv cols
        f32x4 sacc[4] = {};
        #pragma unroll
        for (int ks = 0; ks < 2; ++ks) {
            #pragma unroll
            for (int nf = 0; nf < 4; ++nf) {
                int row = nf * 16 + lm;
                s16x8 bk = ((const s16x8*)Ks)[row * 8 + ((ks*4 + lg) ^ (row & 7))];
                sacc[nf] = __builtin_amdgcn_mfma_f32_16x16x32_bf16(aq[ks], bk, sacc[nf], 0, 0, 0);
            }
        }
        // scale + mask + row max
        float p[4][4], tmax[4];
        #pragma unroll
        for (int j = 0; j < 4; ++j) tmax[j] = -__builtin_inff();
        #pragma unroll
        for (int nf = 0; nf < 4; ++nf) {
            int col = kv0 + nf * 16 + lm;
            bool valid = col < NN;
            #pragma unroll
            for (int j = 0; j < 4; ++j) {
                float s = valid ? sacc[nf][j] * 0.125f : -__builtin_inff();
                p[nf][j] = s;
                tmax[j] = fmaxf(tmax[j], s);
            }
        }
        #pragma unroll
        for (int j = 0; j < 4; ++j) {
            float v = tmax[j];
            v = fmaxf(v, __shfl_xor(v, 1, 16));
            v = fmaxf(v, __shfl_xor(v, 2, 16));
            v = fmaxf(v, __shfl_xor(v, 4, 16));
            v = fmaxf(v, __shfl_xor(v, 8, 16));
            tmax[j] = v;
        }
        float scl[4];
        #pragma unroll
        for (int j = 0; j < 4; ++j) {
            float mn = fmaxf(mrow[j], tmax[j]);
            float sc = __expf(mrow[j] - mn);
            float rs = 0.f;
            #pragma unroll
            for (int nf = 0; nf < 4; ++nf) {
                float pv = __expf(p[nf][j] - mn);
                p[nf][j] = pv;
                rs += pv;
            }
            rs += __shfl_xor(rs, 1, 16);
            rs += __shfl_xor(rs, 2, 16);
            rs += __shfl_xor(rs, 4, 16);
            rs += __shfl_xor(rs, 8, 16);
            lrow[j] = lrow[j] * sc + rs;
            mrow[j] = mn;
            scl[j] = sc;
        }
        #pragma unroll
        for (int df = 0; df < 4; ++df)
            #pragma unroll
            for (int j = 0; j < 4; ++j)
                oacc[df][j] *= scl[j];

        // P -> LDS (bf16), each wave writes its own 16 rows
        #pragma unroll
        for (int nf = 0; nf < 4; ++nf) {
            #pragma unroll
            for (int j = 0; j < 4; ++j) {
                int row = wid * 16 + lg * 4 + j;
                int col = nf * 16 + lm;
                Ps[row * 64 + (col ^ ((row & 7) << 3))] = f2bf(p[nf][j]);
            }
        }
        __syncthreads();

        // O += P V
        #pragma unroll
        for (int ks = 0; ks < 2; ++ks) {
            int prow = wid * 16 + lm;
            s16x8 ap = ((const s16x8*)Ps)[prow * 8 + ((ks*4 + lg) ^ (prow & 7))];
            #pragma unroll
            for (int df = 0; df < 4; ++df) {
                int vrow = df * 16 + lm;
                s16x8 bv = ((const s16x8*)Vts)[vrow * 8 + ((ks*4 + lg) ^ (vrow & 7))];
                oacc[df] = __builtin_amdgcn_mfma_f32_16x16x32_bf16(ap, bv, oacc[df], 0, 0, 0);
            }
        }
    }

    // epilogue: O / l, store bf16 (permuted layout col = h*64 + dk)
    #pragma unroll
    for (int df = 0; df < 4; ++df) {
        int dk = df * 16 + lm;
        #pragma unroll
        for (int j = 0; j < 4; ++j) {
            int rloc = q0 + wid * 16 + lg * 4 + j;
            if (rloc < NN) {
                float v = oacc[df][j] / lrow[j];
                Ow[(rowbase + rloc) * 512 + colbase + dk] = f2bf(v);
            }
        }
    }
}

// ---------------------------------------------------------------------------
// K3: out-projection GEMM + residual.  tmp = o_perm (bf16) @ WtO + X (fp32)
// Same structure as proj_gemm, A already bf16.
// ---------------------------------------------------------------------------
__global__ __launch_bounds__(256) void out_gemm(
    const unsigned short* __restrict__ A, const unsigned short* __restrict__ Bt,
    const float* __restrict__ X, float* __restrict__ Out)
{
    __shared__ unsigned short As[128*64];
    __shared__ unsigned short Bs[128*64];

    int mtile = blockIdx.x, ntile = blockIdx.y;
    int t = threadIdx.x;
    int srow = t >> 1, shalf = t & 1;
    int wid = t >> 6, lane = t & 63;
    int wm = wid >> 1, wn = wid & 1;
    int lm = lane & 15, lg = lane >> 4;

    f32x4 acc[4][4] = {};

    long arow = (long)mtile * 128 + srow;
    bool avalid = arow < MROWS;
    const unsigned short* aptr = A + arow * 512 + shalf * 32;
    const unsigned short* bptr = Bt + (ntile * 128 + srow) * 512 + shalf * 32;

    u32x4 abuf[4], bbuf[4];
    if (avalid) {
        const u32x4* ap = (const u32x4*)aptr;
        #pragma unroll
        for (int i = 0; i < 4; ++i) abuf[i] = ap[i];
    } else {
        #pragma unroll
        for (int i = 0; i < 4; ++i) abuf[i] = 0;
    }
    {
        const u32x4* bp = (const u32x4*)bptr;
        #pragma unroll
        for (int i = 0; i < 4; ++i) bbuf[i] = bp[i];
    }

    for (int kk = 0; kk < 8; ++kk) {
        __syncthreads();
        {
            u32x4* asl = (u32x4*)As;
            u32x4* bsl = (u32x4*)Bs;
            int base = srow * 8, sw = srow & 7;
            #pragma unroll
            for (int s = 0; s < 4; ++s) {
                int slot = shalf * 4 + s;
                asl[base + (slot ^ sw)] = abuf[s];
                bsl[base + (slot ^ sw)] = bbuf[s];
            }
        }
        __syncthreads();
        if (kk < 7) {
            int k0 = (kk + 1) * 64;
            if (avalid) {
                const u32x4* ap = (const u32x4*)(aptr + k0);
                #pragma unroll
                for (int i = 0; i < 4; ++i) abuf[i] = ap[i];
            }
            const u32x4* bp = (const u32x4*)(bptr + k0);
            #pragma unroll
            for (int i = 0; i < 4; ++i) bbuf[i] = bp[i];
        }
        #pragma unroll
        for (int ks = 0; ks < 2; ++ks) {
            s16x8 af[4], bfr[4];
            #pragma unroll
            for (int mf = 0; mf < 4; ++mf) {
                int row = wm * 64 + mf * 16 + lm;
                af[mf] = ((const s16x8*)As)[row * 8 + ((ks*4 + lg) ^ (row & 7))];
            }
            #pragma unroll
            for (int nf = 0; nf < 4; ++nf) {
                int row = wn * 64 + nf * 16 + lm;
                bfr[nf] = ((const s16x8*)Bs)[row * 8 + ((ks*4 + lg) ^ (row & 7))];
            }
            #pragma unroll
            for (int mf = 0; mf < 4; ++mf)
                #pragma unroll
                for (int nf = 0; nf < 4; ++nf)
                    acc[mf][nf] = __builtin_amdgcn_mfma_f32_16x16x32_bf16(af[mf], bfr[nf], acc[mf][nf], 0, 0, 0);
        }
    }

    #pragma unroll
    for (int nf = 0; nf < 4; ++nf) {
        int gcol = ntile * 128 + wn * 64 + nf * 16 + lm;
        #pragma unroll
        for (int mf = 0; mf < 4; ++mf) {
            #pragma unroll
            for (int j = 0; j < 4; ++j) {
                long grow = (long)mtile * 128 + wm * 64 + mf * 16 + lg * 4 + j;
                if (grow < MROWS) {
                    float r = acc[mf][nf][j] + X[grow * 512 + gcol];
                    Out[grow * 512 + gcol] = r;
                }
            }
        }
    }
}

// ---------------------------------------------------------------------------
// K4: LayerNorm over D=512, one wave per row.
// ---------------------------------------------------------------------------
__global__ __launch_bounds__(256) void ln_kernel(
    const float* __restrict__ T, const float* __restrict__ gamma,
    const float* __restrict__ beta, float* __restrict__ Outp)
{
    int wid = threadIdx.x >> 6, lane = threadIdx.x & 63;
    long row = (long)blockIdx.x * 4 + wid;
    const float4* src = (const float4*)(T + row * 512);
    float4 v0 = src[lane * 2], v1 = src[lane * 2 + 1];
    float s  = v0.x + v0.y + v0.z + v0.w + v1.x + v1.y + v1.z + v1.w;
    float sq = v0.x*v0.x + v0.y*v0.y + v0.z*v0.z + v0.w*v0.w
             + v1.x*v1.x + v1.y*v1.y + v1.z*v1.z + v1.w*v1.w;
    #pragma unroll
    for (int m = 1; m < 64; m <<= 1) {
        s  += __shfl_xor(s, m);
        sq += __shfl_xor(sq, m);
    }
    float mean = s * (1.f / 512.f);
    float var = sq * (1.f / 512.f) - mean * mean;
    float rstd = rsqrtf(var + 1e-5f);
    const float4* g = (const float4*)gamma;
    const float4* b = (const float4*)beta;
    float4 g0 = g[lane * 2], g1 = g[lane * 2 + 1];
    float4 b0 = b[lane * 2], b1 = b[lane * 2 + 1];
    float4 o0, o1;
    o0.x = (v0.x - mean) * rstd * g0.x + b0.x;
    o0.y = (v0.y - mean) * rstd * g0.y + b0.y;
    o0.z = (v0.z - mean) * rstd * g0.z + b0.z;
    o0.w = (v0.w - mean) * rstd * g0.w + b0.w;
    o1.x = (v1.x - mean) * rstd * g1.x + b1.x;
    o1.y = (v1.y - mean) * rstd * g1.y + b1.y;
    o1.z = (v1.z - mean) * rstd * g1.z + b1.z;
    o1.w = (v1.w - mean) * rstd * g1.w + b1.w;
    float4* dst = (float4*)(Outp + row * 512);
    dst[lane * 2]     = o0;
    dst[lane * 2 + 1] = o1;
}

// ---------------------------------------------------------------------------
extern "C" void kernel_launch(void* const* d_in, const int* in_sizes, int n_in,
                              void* d_out, int out_size, void* d_ws, size_t ws_size,
                              hipStream_t stream)
{
    const float* X  = (const float*)d_in[0];
    const float* Q  = (const float*)d_in[1];
    const float* K  = (const float*)d_in[2];
    const float* V  = (const float*)d_in[3];
    const float* Wh = (const float*)d_in[4];
    const float* bi = (const float*)d_in[5];
    const float* Wo = (const float*)d_in[6];
    const float* gamma = (const float*)d_in[7];
    const float* beta  = (const float*)d_in[8];

    char* ws = (char*)d_ws;
    const size_t msz = (size_t)MROWS * 512 * 2;     // one bf16 matrix = 31,948,800 B
    unsigned short* q_ws = (unsigned short*)(ws);
    unsigned short* k_ws = (unsigned short*)(ws + msz);
    unsigned short* v_ws = (unsigned short*)(ws + 2 * msz);
    unsigned short* o_ws = (unsigned short*)(ws + 3 * msz);
    unsigned short* WtH  = (unsigned short*)(ws + 4 * msz);
    unsigned short* WtO  = (unsigned short*)(ws + 4 * msz + (size_t)3*512*512*2);
    float* biasp         = (float*)(ws + 4 * msz + (size_t)4*512*512*2);
    float* tmp           = (float*)(ws);  // reuses q_ws+k_ws (dead after attention); 64 MB

    prep_kernel<<<4102, 256, 0, stream>>>(Wh, bi, Wo, WtH, WtO, biasp);

    dim3 g1(244, 4, 3);
    proj_gemm<<<g1, 256, 0, stream>>>(Q, K, V, WtH, biasp, q_ws, k_ws, v_ws);

    dim3 g2(6, 8, 96);
    attn_kernel<<<g2, 256, 0, stream>>>(q_ws, k_ws, v_ws, o_ws);

    dim3 g3(244, 4, 1);
    out_gemm<<<g3, 256, 0, stream>>>(o_ws, WtO, X, tmp);

    ln_kernel<<<7800, 256, 0, stream>>>(tmp, gamma, beta, (float*)d_out);
}

// Round 2
// 393.583 us; speedup vs baseline: 1.1514x; 1.1514x over previous
//
#include <hip/hip_runtime.h>
#include <hip/hip_bf16.h>
#include <stdint.h>

// Problem constants
#define BB 4
#define TT 24
#define NN 325          // sequence length per (b,t)
#define DD 512
#define NH 8
#define DKH 64          // d_k per head
#define MROWS (BB*TT*NN)   // 31200 total rows
#define BTC (BB*TT)        // 96

typedef __attribute__((ext_vector_type(4))) float f32x4;
typedef __attribute__((ext_vector_type(8))) short s16x8;
typedef __attribute__((ext_vector_type(4))) unsigned int u32x4;

__device__ __forceinline__ unsigned short f2bf(float f) {
    union { float f; unsigned int u; } x; x.f = f;
    unsigned int u = x.u;
    u += 0x7fffu + ((u >> 16) & 1u);   // RNE
    return (unsigned short)(u >> 16);
}
__device__ __forceinline__ unsigned int pack2(float a, float b) {
    return (unsigned int)f2bf(a) | ((unsigned int)f2bf(b) << 16);
}
// packed f32->bf16 (RNE) via HW instruction; non-volatile so scheduler may move it
__device__ __forceinline__ unsigned int cvt2(float a, float b) {
    unsigned int r;
    asm("v_cvt_pk_bf16_f32 %0, %1, %2" : "=v"(r) : "v"(a), "v"(b));
    return r;
}
union HU { s16x8 h; u32x4 u; };

__device__ __forceinline__ void gload16(const void* g, void* l) {
    __builtin_amdgcn_global_load_lds((const __attribute__((address_space(1))) void*)g,
                                     (__attribute__((address_space(3))) void*)l, 16, 0, 0);
}

// ---------------------------------------------------------------------------
// K0: weight prep. Permute head-interleaved columns (d = dk*8+h  ->  h*64+dk),
// transpose to [n][k] layout, convert to bf16.
// ---------------------------------------------------------------------------
__global__ void prep_kernel(const float* __restrict__ Wh, const float* __restrict__ bias,
                            const float* __restrict__ Wo,
                            unsigned short* __restrict__ WtH, unsigned short* __restrict__ WtO,
                            float* __restrict__ biasp)
{
    int idx = blockIdx.x * 256 + threadIdx.x;
    if (idx < 3*512*512) {
        int i = idx >> 18; int rem = idx & 262143;
        int cp = rem >> 9; int e = rem & 511;
        int c = ((cp & 63) << 3) | (cp >> 6);
        WtH[idx] = f2bf(Wh[(i << 18) + (e << 9) + c]);
        return;
    }
    int idx2 = idx - 3*512*512;
    if (idx2 >= 0 && idx2 < 512*512) {
        int c = idx2 >> 9; int ep = idx2 & 511;
        int row = ((ep & 63) << 3) | (ep >> 6);
        WtO[idx2] = f2bf(Wo[(row << 9) + c]);
        return;
    }
    int idx3 = idx2 - 512*512;
    if (idx3 >= 0 && idx3 < 3*512) {
        int i = idx3 >> 9; int cp = idx3 & 511;
        int c = ((cp & 63) << 3) | (cp >> 6);
        biasp[idx3] = bias[(i << 9) + c];
    }
}

// ---------------------------------------------------------------------------
// K1: QKV projection GEMM, m97 structure.
// A fp32 staged to LDS via global_load_lds (pre-swizzled source), converted
// bf16 at fragment read (v_cvt_pk_bf16_f32). B bf16 [n][k] via global_load_lds.
// BM=128 BN=128 BK=64, 256 threads (2x2 waves of 64x64). Single LDS buffer,
// 2 barriers/K-step; cross-block overlap (3 blocks/CU) hides the drain.
// XCD-chunked block swizzle: 2928 wg = 8 XCD x 366.
// ---------------------------------------------------------------------------
__global__ __launch_bounds__(256) void proj_gemm(
    const float* __restrict__ Aq, const float* __restrict__ Ak, const float* __restrict__ Av,
    const unsigned short* __restrict__ Wt, const float* __restrict__ biasp,
    unsigned short* __restrict__ Yq, unsigned short* __restrict__ Yk, unsigned short* __restrict__ Yv)
{
    __shared__ float As[128*64];              // 32 KB, granule-swizzled
    __shared__ unsigned short Bs[128*64];     // 16 KB

    int orig = blockIdx.x;
    int wg = (orig & 7) * 366 + (orig >> 3);  // bijective XCD chunking (2928=8*366)
    int z = wg / 976; int rem = wg - z * 976;
    int mtile = rem >> 2; int ntile = rem & 3;

    const float* A = (z == 0) ? Aq : ((z == 1) ? Ak : Av);
    unsigned short* Y = (z == 0) ? Yq : ((z == 1) ? Yk : Yv);
    const unsigned short* Bt = Wt + z * 512 * 512 + ntile * 128 * 512;
    const float* bias = biasp + z * 512;

    int t = threadIdx.x;
    int wid = t >> 6, lane = t & 63;
    int wm = wid >> 1, wn = wid & 1;
    int lm = lane & 15, lg = lane >> 4;

    long mbase = (long)mtile * 128;
    const float* Abase = A + mbase * 512;

    // Precompute per-lane staging offsets (constant across K-steps).
    // A: 2048 granules of 16B (4 fp32); LDS[row][s'] holds logical slot s'=s^(row&7).
    int aoff[8];
    #pragma unroll
    for (int r = 0; r < 8; ++r) {
        int G = ((r * 4 + wid) << 6) + lane;      // 0..2047
        int row = G >> 4;
        int slot = (G & 15) ^ (row & 7);
        int rowc = row;
        if (mbase + row > MROWS - 1) rowc = (int)(MROWS - 1 - mbase);
        aoff[r] = rowc * 512 + slot * 4;
    }
    // B: 1024 granules of 16B (8 bf16)
    int boff[4];
    #pragma unroll
    for (int r = 0; r < 4; ++r) {
        int G = ((r * 4 + wid) << 6) + lane;      // 0..1023
        int row = G >> 3;
        int slot = (G & 7) ^ (row & 7);
        boff[r] = row * 512 + slot * 8;
    }

    f32x4 acc[4][4] = {};

    for (int kk = 0; kk < 8; ++kk) {
        const int k0 = kk * 64;
        __syncthreads();                           // prev compute done reading LDS
        #pragma unroll
        for (int r = 0; r < 8; ++r)
            gload16(Abase + aoff[r] + k0, &As[(r * 4 + wid) << 8]);
        #pragma unroll
        for (int r = 0; r < 4; ++r)
            gload16(Bt + boff[r] + k0, &Bs[(r * 4 + wid) << 9]);
        asm volatile("s_waitcnt vmcnt(0)" ::: "memory");
        __syncthreads();

        #pragma unroll
        for (int ks = 0; ks < 2; ++ks) {
            s16x8 afr[4], bfr[4];
            #pragma unroll
            for (int mf = 0; mf < 4; ++mf) {
                int row = wm * 64 + mf * 16 + lm;
                int sw = row & 7;
                int s0 = (ks * 4 + lg) * 2;
                f32x4 a0 = ((const f32x4*)As)[row * 16 + (s0 ^ sw)];
                f32x4 a1 = ((const f32x4*)As)[row * 16 + ((s0 + 1) ^ sw)];
                HU u;
                u.u[0] = cvt2(a0[0], a0[1]); u.u[1] = cvt2(a0[2], a0[3]);
                u.u[2] = cvt2(a1[0], a1[1]); u.u[3] = cvt2(a1[2], a1[3]);
                afr[mf] = u.h;
            }
            #pragma unroll
            for (int nf = 0; nf < 4; ++nf) {
                int row = wn * 64 + nf * 16 + lm;
                bfr[nf] = ((const s16x8*)Bs)[row * 8 + ((ks * 4 + lg) ^ (row & 7))];
            }
            #pragma unroll
            for (int mf = 0; mf < 4; ++mf)
                #pragma unroll
                for (int nf = 0; nf < 4; ++nf)
                    acc[mf][nf] = __builtin_amdgcn_mfma_f32_16x16x32_bf16(afr[mf], bfr[nf], acc[mf][nf], 0, 0, 0);
        }
    }

    #pragma unroll
    for (int nf = 0; nf < 4; ++nf) {
        int gcol = ntile * 128 + wn * 64 + nf * 16 + lm;
        float bv = bias[gcol];
        #pragma unroll
        for (int mf = 0; mf < 4; ++mf) {
            #pragma unroll
            for (int j = 0; j < 4; ++j) {
                long grow = mbase + wm * 64 + mf * 16 + lg * 4 + j;
                if (grow < MROWS)
                    Y[grow * 512 + gcol] = f2bf(acc[mf][nf][j] + bv);
            }
        }
    }
}

// ---------------------------------------------------------------------------
// K2: attention (unchanged this round).
// ---------------------------------------------------------------------------
__global__ __launch_bounds__(256) void attn_kernel(
    const unsigned short* __restrict__ Qw, const unsigned short* __restrict__ Kw,
    const unsigned short* __restrict__ Vw, unsigned short* __restrict__ Ow)
{
    __shared__ unsigned short Qs[64*64];
    __shared__ unsigned short Ks[64*64];
    __shared__ unsigned short Vts[64*64];
    __shared__ unsigned short Ps[64*64];

    int qc = blockIdx.x;
    int h  = blockIdx.y;
    int bt = blockIdx.z;
    int t = threadIdx.x;
    int wid = t >> 6, lane = t & 63, lm = lane & 15, lg = lane >> 4;

    long rowbase = (long)bt * NN;
    int colbase = h * 64;
    int q0 = qc * 64;

    {
        int i = t >> 2, quarter = t & 3;
        const u32x4* src = (const u32x4*)(Qw + (rowbase + q0 + i) * 512 + colbase);
        u32x4* dst = (u32x4*)Qs;
        #pragma unroll
        for (int s = 0; s < 2; ++s) {
            int slot = quarter + s * 4;
            u32x4 v = 0;
            if (q0 + i < NN) v = src[slot];
            dst[i * 8 + (slot ^ (i & 7))] = v;
        }
    }
    __syncthreads();
    s16x8 aq[2];
    {
        int row = wid * 16 + lm;
        aq[0] = ((const s16x8*)Qs)[row * 8 + ((0 + lg) ^ (row & 7))];
        aq[1] = ((const s16x8*)Qs)[row * 8 + ((4 + lg) ^ (row & 7))];
    }

    f32x4 oacc[4] = {};
    float mrow[4], lrow[4];
    #pragma unroll
    for (int j = 0; j < 4; ++j) { mrow[j] = -__builtin_inff(); lrow[j] = 0.f; }

    for (int kv0 = 0; kv0 < NN; kv0 += 64) {
        __syncthreads();
        {
            int i = t >> 2, quarter = t & 3;
            const u32x4* src = (const u32x4*)(Kw + (rowbase + kv0 + i) * 512 + colbase);
            u32x4* dst = (u32x4*)Ks;
            #pragma unroll
            for (int s = 0; s < 2; ++s) {
                int slot = quarter + s * 4;
                u32x4 v = 0;
                if (kv0 + i < NN) v = src[slot];
                dst[i * 8 + (slot ^ (i & 7))] = v;
            }
        }
        {
            int i = t >> 2, quarter = t & 3;
            unsigned short vb[16] __attribute__((aligned(16)));
            if (kv0 + i < NN) {
                const u32x4* src = (const u32x4*)(Vw + (rowbase + kv0 + i) * 512 + colbase + quarter * 16);
                *((u32x4*)vb) = src[0];
                *((u32x4*)(vb + 8)) = src[1];
            } else {
                #pragma unroll
                for (int x = 0; x < 16; ++x) vb[x] = 0;
            }
            #pragma unroll
            for (int x = 0; x < 16; ++x) {
                int dk = quarter * 16 + x;
                Vts[dk * 64 + (i ^ ((dk & 7) << 3))] = vb[x];
            }
        }
        __syncthreads();

        f32x4 sacc[4] = {};
        #pragma unroll
        for (int ks = 0; ks < 2; ++ks) {
            #pragma unroll
            for (int nf = 0; nf < 4; ++nf) {
                int row = nf * 16 + lm;
                s16x8 bk = ((const s16x8*)Ks)[row * 8 + ((ks*4 + lg) ^ (row & 7))];
                sacc[nf] = __builtin_amdgcn_mfma_f32_16x16x32_bf16(aq[ks], bk, sacc[nf], 0, 0, 0);
            }
        }
        float p[4][4], tmax[4];
        #pragma unroll
        for (int j = 0; j < 4; ++j) tmax[j] = -__builtin_inff();
        #pragma unroll
        for (int nf = 0; nf < 4; ++nf) {
            int col = kv0 + nf * 16 + lm;
            bool valid = col < NN;
            #pragma unroll
            for (int j = 0; j < 4; ++j) {
                float s = valid ? sacc[nf][j] * 0.125f : -__builtin_inff();
                p[nf][j] = s;
                tmax[j] = fmaxf(tmax[j], s);
            }
        }
        #pragma unroll
        for (int j = 0; j < 4; ++j) {
            float v = tmax[j];
            v = fmaxf(v, __shfl_xor(v, 1, 16));
            v = fmaxf(v, __shfl_xor(v, 2, 16));
            v = fmaxf(v, __shfl_xor(v, 4, 16));
            v = fmaxf(v, __shfl_xor(v, 8, 16));
            tmax[j] = v;
        }
        float scl[4];
        #pragma unroll
        for (int j = 0; j < 4; ++j) {
            float mn = fmaxf(mrow[j], tmax[j]);
            float sc = __expf(mrow[j] - mn);
            float rs = 0.f;
            #pragma unroll
            for (int nf = 0; nf < 4; ++nf) {
                float pv = __expf(p[nf][j] - mn);
                p[nf][j] = pv;
                rs += pv;
            }
            rs += __shfl_xor(rs, 1, 16);
            rs += __shfl_xor(rs, 2, 16);
            rs += __shfl_xor(rs, 4, 16);
            rs += __shfl_xor(rs, 8, 16);
            lrow[j] = lrow[j] * sc + rs;
            mrow[j] = mn;
            scl[j] = sc;
        }
        #pragma unroll
        for (int df = 0; df < 4; ++df)
            #pragma unroll
            for (int j = 0; j < 4; ++j)
                oacc[df][j] *= scl[j];

        #pragma unroll
        for (int nf = 0; nf < 4; ++nf) {
            #pragma unroll
            for (int j = 0; j < 4; ++j) {
                int row = wid * 16 + lg * 4 + j;
                int col = nf * 16 + lm;
                Ps[row * 64 + (col ^ ((row & 7) << 3))] = f2bf(p[nf][j]);
            }
        }
        __syncthreads();

        #pragma unroll
        for (int ks = 0; ks < 2; ++ks) {
            int prow = wid * 16 + lm;
            s16x8 ap = ((const s16x8*)Ps)[prow * 8 + ((ks*4 + lg) ^ (prow & 7))];
            #pragma unroll
            for (int df = 0; df < 4; ++df) {
                int vrow = df * 16 + lm;
                s16x8 bv = ((const s16x8*)Vts)[vrow * 8 + ((ks*4 + lg) ^ (vrow & 7))];
                oacc[df] = __builtin_amdgcn_mfma_f32_16x16x32_bf16(ap, bv, oacc[df], 0, 0, 0);
            }
        }
    }

    #pragma unroll
    for (int df = 0; df < 4; ++df) {
        int dk = df * 16 + lm;
        #pragma unroll
        for (int j = 0; j < 4; ++j) {
            int rloc = q0 + wid * 16 + lg * 4 + j;
            if (rloc < NN) {
                float v = oacc[df][j] / lrow[j];
                Ow[(rowbase + rloc) * 512 + colbase + dk] = f2bf(v);
            }
        }
    }
}

// ---------------------------------------------------------------------------
// K3: out-projection + residual, m97 structure (pure bf16 LDS via
// global_load_lds). Writes bf16 pre-LN tensor. XCD chunking: 976 = 8*122.
// ---------------------------------------------------------------------------
__global__ __launch_bounds__(256) void out_gemm(
    const unsigned short* __restrict__ A, const unsigned short* __restrict__ Bt0,
    const float* __restrict__ X, unsigned short* __restrict__ Out)
{
    __shared__ unsigned short As[128*64];     // 16 KB
    __shared__ unsigned short Bs[128*64];     // 16 KB

    int orig = blockIdx.x;
    int wg = (orig & 7) * 122 + (orig >> 3);
    int mtile = wg >> 2; int ntile = wg & 3;

    const unsigned short* Bt = Bt0 + ntile * 128 * 512;

    int t = threadIdx.x;
    int wid = t >> 6, lane = t & 63;
    int wm = wid >> 1, wn = wid & 1;
    int lm = lane & 15, lg = lane >> 4;

    long mbase = (long)mtile * 128;
    const unsigned short* Abase = A + mbase * 512;

    int aoff[4], boff[4];
    #pragma unroll
    for (int r = 0; r < 4; ++r) {
        int G = ((r * 4 + wid) << 6) + lane;      // 0..1023
        int row = G >> 3;
        int slot = (G & 7) ^ (row & 7);
        int rowc = row;
        if (mbase + row > MROWS - 1) rowc = (int)(MROWS - 1 - mbase);
        aoff[r] = rowc * 512 + slot * 8;
        boff[r] = row * 512 + slot * 8;
    }

    f32x4 acc[4][4] = {};

    for (int kk = 0; kk < 8; ++kk) {
        const int k0 = kk * 64;
        __syncthreads();
        #pragma unroll
        for (int r = 0; r < 4; ++r)
            gload16(Abase + aoff[r] + k0, &As[(r * 4 + wid) << 9]);
        #pragma unroll
        for (int r = 0; r < 4; ++r)
            gload16(Bt + boff[r] + k0, &Bs[(r * 4 + wid) << 9]);
        asm volatile("s_waitcnt vmcnt(0)" ::: "memory");
        __syncthreads();

        #pragma unroll
        for (int ks = 0; ks < 2; ++ks) {
            s16x8 afr[4], bfr[4];
            #pragma unroll
            for (int mf = 0; mf < 4; ++mf) {
                int row = wm * 64 + mf * 16 + lm;
                afr[mf] = ((const s16x8*)As)[row * 8 + ((ks * 4 + lg) ^ (row & 7))];
            }
            #pragma unroll
            for (int nf = 0; nf < 4; ++nf) {
                int row = wn * 64 + nf * 16 + lm;
                bfr[nf] = ((const s16x8*)Bs)[row * 8 + ((ks * 4 + lg) ^ (row & 7))];
            }
            #pragma unroll
            for (int mf = 0; mf < 4; ++mf)
                #pragma unroll
                for (int nf = 0; nf < 4; ++nf)
                    acc[mf][nf] = __builtin_amdgcn_mfma_f32_16x16x32_bf16(afr[mf], bfr[nf], acc[mf][nf], 0, 0, 0);
        }
    }

    #pragma unroll
    for (int nf = 0; nf < 4; ++nf) {
        int gcol = ntile * 128 + wn * 64 + nf * 16 + lm;
        #pragma unroll
        for (int mf = 0; mf < 4; ++mf) {
            #pragma unroll
            for (int j = 0; j < 4; ++j) {
                long grow = mbase + wm * 64 + mf * 16 + lg * 4 + j;
                if (grow < MROWS) {
                    float r = acc[mf][nf][j] + X[grow * 512 + gcol];
                    Out[grow * 512 + gcol] = f2bf(r);
                }
            }
        }
    }
}

// ---------------------------------------------------------------------------
// K4: LayerNorm over D=512 (bf16 input, fp32 output), one wave per row.
// ---------------------------------------------------------------------------
__global__ __launch_bounds__(256) void ln_kernel(
    const unsigned short* __restrict__ T, const float* __restrict__ gamma,
    const float* __restrict__ beta, float* __restrict__ Outp)
{
    int wid = threadIdx.x >> 6, lane = threadIdx.x & 63;
    long row = (long)blockIdx.x * 4 + wid;
    s16x8 h = ((const s16x8*)(T + row * 512))[lane];
    float v[8];
    #pragma unroll
    for (int j = 0; j < 8; ++j) {
        union { float f; unsigned int u; } x;
        x.u = ((unsigned int)(unsigned short)h[j]) << 16;
        v[j] = x.f;
    }
    float s = 0.f, sq = 0.f;
    #pragma unroll
    for (int j = 0; j < 8; ++j) { s += v[j]; sq += v[j] * v[j]; }
    #pragma unroll
    for (int m = 1; m < 64; m <<= 1) {
        s  += __shfl_xor(s, m);
        sq += __shfl_xor(sq, m);
    }
    float mean = s * (1.f / 512.f);
    float var = sq * (1.f / 512.f) - mean * mean;
    float rstd = rsqrtf(var + 1e-5f);
    const float4* g = (const float4*)gamma;
    const float4* b = (const float4*)beta;
    float4 g0 = g[lane * 2], g1 = g[lane * 2 + 1];
    float4 b0 = b[lane * 2], b1 = b[lane * 2 + 1];
    float4 o0, o1;
    o0.x = (v[0] - mean) * rstd * g0.x + b0.x;
    o0.y = (v[1] - mean) * rstd * g0.y + b0.y;
    o0.z = (v[2] - mean) * rstd * g0.z + b0.z;
    o0.w = (v[3] - mean) * rstd * g0.w + b0.w;
    o1.x = (v[4] - mean) * rstd * g1.x + b1.x;
    o1.y = (v[5] - mean) * rstd * g1.y + b1.y;
    o1.z = (v[6] - mean) * rstd * g1.z + b1.z;
    o1.w = (v[7] - mean) * rstd * g1.w + b1.w;
    float4* dst = (float4*)(Outp + row * 512);
    dst[lane * 2]     = o0;
    dst[lane * 2 + 1] = o1;
}

// ---------------------------------------------------------------------------
extern "C" void kernel_launch(void* const* d_in, const int* in_sizes, int n_in,
                              void* d_out, int out_size, void* d_ws, size_t ws_size,
                              hipStream_t stream)
{
    const float* X  = (const float*)d_in[0];
    const float* Q  = (const float*)d_in[1];
    const float* K  = (const float*)d_in[2];
    const float* V  = (const float*)d_in[3];
    const float* Wh = (const float*)d_in[4];
    const float* bi = (const float*)d_in[5];
    const float* Wo = (const float*)d_in[6];
    const float* gamma = (const float*)d_in[7];
    const float* beta  = (const float*)d_in[8];

    char* ws = (char*)d_ws;
    const size_t msz = (size_t)MROWS * 512 * 2;     // one bf16 matrix ~31.9 MB
    unsigned short* q_ws = (unsigned short*)(ws);
    unsigned short* k_ws = (unsigned short*)(ws + msz);
    unsigned short* v_ws = (unsigned short*)(ws + 2 * msz);
    unsigned short* o_ws = (unsigned short*)(ws + 3 * msz);
    unsigned short* WtH  = (unsigned short*)(ws + 4 * msz);
    unsigned short* WtO  = (unsigned short*)(ws + 4 * msz + (size_t)3*512*512*2);
    float* biasp         = (float*)(ws + 4 * msz + (size_t)4*512*512*2);
    unsigned short* tmpb = q_ws;   // pre-LN bf16 tensor; q dead after attention

    prep_kernel<<<4102, 256, 0, stream>>>(Wh, bi, Wo, WtH, WtO, biasp);

    proj_gemm<<<2928, 256, 0, stream>>>(Q, K, V, WtH, biasp, q_ws, k_ws, v_ws);

    dim3 g2(6, 8, 96);
    attn_kernel<<<g2, 256, 0, stream>>>(q_ws, k_ws, v_ws, o_ws);

    out_gemm<<<976, 256, 0, stream>>>(o_ws, WtO, X, tmpb);

    ln_kernel<<<7800, 256, 0, stream>>>(tmpb, gamma, beta, (float*)d_out);
}